// Round 4
// baseline (81.372 us; speedup 1.0000x reference)
//
#include <hip/hip_runtime.h>

// SGNN projection, round 4: lane-per-output, tightened inner-loop codegen.
//
// Math (M = 2^31-1 Mersenne, HALF = 2^30-1):
//   centered(v) = ((v + HALF) mod M) - HALF  ->  p2 = sig*seed + HALF (one v_mad_u64_u32,
//   the +HALF rides free in the mad addend). Masked slots (sig=0 -> residue HALF)
//   contribute 0 after the linear -HALF, hoisted to a single -128*HALF.
//   Fold: s = (p2>>31) + (p2 & M) <= 2^32-4 < 2M ALWAYS (sig,seed <= 2^31-2), so
//   residue = s - M*[s>=M] exactly, single compare. Accumulate sum(s) u64 + q=[s>=M]
//   count; centered partial = sum - M*q - 128*HALF, exact int64.
//   p2>>31 forced to one v_alignbit_b32 via builtin.
//
// Element cost: mad_u64 + alignbit + and + add + cmp + addc + add_co + addc = 8 VALU slots.
// 88.1M elems * 8 / 78.6T slots/s ~= 9 us floor for the main kernel.

#define M31    2147483647u   // 2^31 - 1
#define HALF_B 1073741823u   // 2^30 - 1

__global__ __launch_bounds__(64) void sgnn_prep_kernel(
    const int* __restrict__ sig,    // [3, B, 128]
    const int* __restrict__ mask,   // [3, B, 128]
    unsigned* __restrict__ msig,    // [3, B, 128] mask-zeroed
    float* __restrict__ invc)       // [3, B]  = 1/(max(cnt,1)*HALF)
{
    const int row = blockIdx.x;          // p*nbatch + b
    const int t   = threadIdx.x;
    const int g0  = row * 128 + t;
    const int g1  = g0 + 64;
    const int mk0 = mask[g0], mk1 = mask[g1];
    msig[g0] = mk0 ? (unsigned)sig[g0] : 0u;
    msig[g1] = mk1 ? (unsigned)sig[g1] : 0u;
    const unsigned long long b0 = __ballot(mk0 != 0);
    const unsigned long long b1 = __ballot(mk1 != 0);
    if (t == 0) {
        int c = __popcll(b0) + __popcll(b1);
        if (c < 1) c = 1;
        invc[row] = 1.0f / ((float)c * 1073741823.0f);
    }
}

__device__ __forceinline__ void acc_elem(unsigned v, unsigned seed,
                                         unsigned long long& sum, unsigned& q) {
    const unsigned long long p2 =
        (unsigned long long)v * (unsigned long long)seed + (unsigned long long)HALF_B;
    const unsigned lo = (unsigned)p2;
    const unsigned hi = (unsigned)(p2 >> 32);
    const unsigned s  = __builtin_amdgcn_alignbit(hi, lo, 31) + (lo & 0x7FFFFFFFu);
    q   += (s >= M31);
    sum += s;
}

__global__ __launch_bounds__(256, 8) void sgnn_main_kernel(
    const unsigned* __restrict__ msig,  // [3, B, 128]
    const float* __restrict__ invc,     // [3, B]
    const int* __restrict__ seeds,      // [672]
    float* __restrict__ out,            // [B, 672] == flat[t]
    int nbatch)
{
    const unsigned t = blockIdx.x * 256u + threadIdx.x;  // [0, nbatch*672), exact grid
    // b = floor(t/672) = floor((t>>5)/21), exact for t < 2^21 via magic 99865 = ceil(2^21/21)
    const unsigned x = t >> 5;
    const unsigned b = (x * 99865u) >> 21;
    const unsigned h = t - 672u * b;
    const int p = (h < 112u) ? 0 : (h < 336u) ? 1 : 2;

    const unsigned* __restrict__ rp = msig + (unsigned)(p * nbatch + b) * 128u;
    const unsigned seed = (unsigned)seeds[h];

    unsigned long long sum0 = 0, sum1 = 0;  // s < 2^32 each; 128 elems < 2^39, exact
    unsigned q0 = 0, q1 = 0;                // count of s >= M

    #pragma unroll 2
    for (int mm = 0; mm < 128; mm += 16) {
        const uint4 a = *(const uint4*)(rp + mm);
        const uint4 c = *(const uint4*)(rp + mm + 4);
        const uint4 d = *(const uint4*)(rp + mm + 8);
        const uint4 e = *(const uint4*)(rp + mm + 12);
        acc_elem(a.x, seed, sum0, q0); acc_elem(a.y, seed, sum1, q1);
        acc_elem(a.z, seed, sum0, q0); acc_elem(a.w, seed, sum1, q1);
        acc_elem(c.x, seed, sum0, q0); acc_elem(c.y, seed, sum1, q1);
        acc_elem(c.z, seed, sum0, q0); acc_elem(c.w, seed, sum1, q1);
        acc_elem(d.x, seed, sum0, q0); acc_elem(d.y, seed, sum1, q1);
        acc_elem(d.z, seed, sum0, q0); acc_elem(d.w, seed, sum1, q1);
        acc_elem(e.x, seed, sum0, q0); acc_elem(e.y, seed, sum1, q1);
        acc_elem(e.z, seed, sum0, q0); acc_elem(e.w, seed, sum1, q1);
    }

    const long long centered = (long long)(sum0 + sum1)
                             - (long long)(q0 + q1) * 2147483647LL
                             - 128LL * 1073741823LL;
    out[t] = (float)centered * invc[p * nbatch + b];
}

extern "C" void kernel_launch(void* const* d_in, const int* in_sizes, int n_in,
                              void* d_out, int out_size, void* d_ws, size_t ws_size,
                              hipStream_t stream) {
    const int* sig   = (const int*)d_in[0];
    const int* mask  = (const int*)d_in[1];
    const int* seeds = (const int*)d_in[2];
    float* out = (float*)d_out;

    const int nbatch = in_sizes[0] / (3 * 128);        // 1024
    unsigned* msig = (unsigned*)d_ws;                   // 3*nbatch*128 u32
    float* invc = (float*)((char*)d_ws + (size_t)(3 * nbatch * 128) * 4);  // 3*nbatch f32

    sgnn_prep_kernel<<<dim3(3 * nbatch), dim3(64), 0, stream>>>(sig, mask, msig, invc);
    const int total = nbatch * 672;                     // 688128 = 2688 * 256 exactly
    sgnn_main_kernel<<<dim3(total / 256), dim3(256), 0, stream>>>(msig, invc, seeds, out, nbatch);
}